// Round 7
// baseline (26.950 us; speedup 1.0000x reference)
//
#include <hip/hip_runtime.h>

#define NCLS 10
#define IGN 10
#define HW_ (512 * 512)          // 262144 = 2^18
#define BATCH 8
#define NPIX (BATCH * HW_)       // 2097152
#define THREADS 128
#define PPT 8                    // px per thread (2 x float4 per channel)
#define BLOCK_PX (THREADS * PPT) // 1024
#define NBLOCKS (NPIX / BLOCK_PX)      // 2048 -> 8 blocks/CU, all resident
#define STAT_STRIDE 16
#define LAMBDA_UNC 0.5f
#define LOG2E 1.4426950408889634f
#define LN2 0.6931471805599453f

// Per-thread private LDS histogram region: 33 floats (3 fields x 10 classes
// + 3 dump slots for ignore pixels). Stride 33 ≡ 1 (mod 32) spreads banks.
#define RSTRIDE 33
#define HISTSZ (THREADS * RSTRIDE)   // 4224 floats = 16896 B

__global__ void awce_zero_stats(float* __restrict__ stats) {
    int i = threadIdx.x;
    if (i < 30 * STAT_STRIDE) stats[i] = 0.0f;
}

template <bool ATOMIC>
__global__ __launch_bounds__(THREADS, 4) void awce_main(
    const float* __restrict__ logits,
    const int* __restrict__ targets,
    float* __restrict__ outbuf)
{
    const int tid = threadIdx.x;
    const int wave = tid >> 6;
    const int lane = tid & 63;

    __shared__ float hist[HISTSZ];
    __shared__ float red[2][32];

    const int g0 = blockIdx.x * BLOCK_PX;      // 1024 | HW_ -> no batch cross
    const int b = g0 >> 18;
    const int hw0 = g0 & (HW_ - 1);
    const float* lbase = logits + (size_t)b * (NCLS * (size_t)HW_) + hw0;

    // ---- issue ALL 22 loads back-to-back (max MLP), pinned before compute ----
    float4 xl[2][NCLS];
    int4 tl[2];
#pragma unroll
    for (int h = 0; h < 2; ++h) {
        const int po = h * 512 + tid * 4;      // fully coalesced per instr
#pragma unroll
        for (int c = 0; c < NCLS; ++c)
            xl[h][c] = *reinterpret_cast<const float4*>(lbase + (size_t)c * HW_ + po);
        tl[h] = *reinterpret_cast<const int4*>(targets + g0 + po);
    }
    // zero the hist while loads fly (LDS writes don't touch vmcnt)
#pragma unroll
    for (int i = 0; i < RSTRIDE; ++i) hist[tid + i * THREADS] = 0.0f;
    __builtin_amdgcn_sched_barrier(0);   // don't sink loads into the compute
    __syncthreads();                     // hist zeroing visible (cheap, once)

    float* hreg = &hist[tid * RSTRIDE];

#pragma unroll
    for (int h = 0; h < 2; ++h) {
        const float4* xv = xl[h];
        const int tt[4] = {tl[h].x, tl[h].y, tl[h].z, tl[h].w};
#pragma unroll
        for (int j = 0; j < 4; ++j) {
            const int tj = tt[j];
            const int tc = (tj != IGN) ? tj : NCLS;   // NCLS -> dump slots
            float x[NCLS];
#pragma unroll
            for (int c = 0; c < NCLS; ++c)
                x[c] = (j == 0) ? xv[c].x : (j == 1) ? xv[c].y : (j == 2) ? xv[c].z : xv[c].w;
            float m = x[0];
#pragma unroll
            for (int c = 1; c < NCLS; ++c) m = fmaxf(m, x[c]);
            const float nm2 = -m * LOG2E;
            float sum = 0.f, dot = 0.f, xt = 0.f;
#pragma unroll
            for (int c = 0; c < NCLS; ++c) {
                const float e = __builtin_amdgcn_exp2f(fmaf(x[c], LOG2E, nm2));
                sum += e;
                dot = fmaf(e, x[c], dot);
                xt = (tc == c) ? x[c] : xt;
            }
            const float lse = fmaf(__builtin_amdgcn_logf(sum), LN2, m);
            const float rs = __builtin_amdgcn_rcpf(sum);
            const float ent = fmaf(-dot, rs, lse);
            const float ce = lse - xt;
            float* p = hreg + 3 * tc;
            p[0] += 1.0f;
            p[1] += ent;
            p[2] += ce;
        }
    }

    __syncthreads();

    // Stage 1: each wave reduces its 64 regions. Lane o<30: field f=o/10,
    // class c=o%10, region offset 3c+f (distinct 0..29 -> conflict-free).
    if (lane < 30) {
        const int f = (lane >= 20) ? 2 : ((lane >= 10) ? 1 : 0);
        const int c = lane - f * 10;
        const int off = 3 * c + f;
        float v = 0.f;
#pragma unroll
        for (int r = 0; r < 64; ++r) v += hist[(wave * 64 + r) * RSTRIDE + off];
        red[wave][lane] = v;
    }
    __syncthreads();

    // Stage 2: combine 2 wave-partials; stat index = f*10+c = lane id.
    if (tid < 30) {
        float v = red[0][tid] + red[1][tid];
        if (ATOMIC) {
            atomicAdd(&outbuf[tid * STAT_STRIDE], v);
        } else {
            outbuf[tid * NBLOCKS + blockIdx.x] = v;
        }
    }
}

// Reduce 30 x NBLOCKS partials, compute final loss. One block, 512 threads.
__global__ __launch_bounds__(512) void awce_final_partials(
    const float* __restrict__ partials, float* __restrict__ out)
{
    __shared__ float sred[32];
    const int wave = threadIdx.x >> 6;
    const int lane = threadIdx.x & 63;
#pragma unroll
    for (int k = 0; k < 4; ++k) {
        const int c = wave + k * 8;
        if (c < 30) {
            const float* col = partials + (size_t)c * NBLOCKS;
            float s = 0.f;
#pragma unroll
            for (int i = 0; i < NBLOCKS / 64; ++i) s += col[lane + 64 * i];
#pragma unroll
            for (int o = 32; o >= 1; o >>= 1) s += __shfl_xor(s, o);
            if (lane == 0) sred[c] = s;
        }
    }
    __syncthreads();
    if (threadIdx.x == 0) {
        float cnt[NCLS], es[NCLS], cs[NCLS];
        float nv = 0.f;
#pragma unroll
        for (int c = 0; c < NCLS; ++c) {
            cnt[c] = sred[c];
            es[c]  = sred[10 + c];
            cs[c]  = sred[20 + c];
            nv += cnt[c];
        }
        float loss = 0.f;
#pragma unroll
        for (int c = 0; c < NCLS; ++c) {
            float wb = 0.f;
            if (cnt[c] > 0.f && nv > 0.f) wb = (nv - cnt[c]) / fmaxf(nv, 1.f);
            const float em = (cnt[c] > 0.f) ? es[c] / fmaxf(cnt[c], 1.f) : 0.f;
            const float wc = wb * (1.f + LAMBDA_UNC * em);
            loss = fmaf(cs[c], wc, loss);
        }
        out[0] = loss / (nv + 1e-6f);
    }
}

__global__ void awce_final_atomic(const float* __restrict__ stats, float* __restrict__ out) {
    if (threadIdx.x == 0) {
        float cnt[NCLS], es[NCLS], cs[NCLS];
        float nv = 0.f;
#pragma unroll
        for (int c = 0; c < NCLS; ++c) {
            cnt[c] = stats[c * STAT_STRIDE];
            es[c]  = stats[(10 + c) * STAT_STRIDE];
            cs[c]  = stats[(20 + c) * STAT_STRIDE];
            nv += cnt[c];
        }
        float loss = 0.f;
#pragma unroll
        for (int c = 0; c < NCLS; ++c) {
            float wb = 0.f;
            if (cnt[c] > 0.f && nv > 0.f) wb = (nv - cnt[c]) / fmaxf(nv, 1.f);
            const float em = (cnt[c] > 0.f) ? es[c] / fmaxf(cnt[c], 1.f) : 0.f;
            const float wc = wb * (1.f + LAMBDA_UNC * em);
            loss = fmaf(cs[c], wc, loss);
        }
        out[0] = loss / (nv + 1e-6f);
    }
}

extern "C" void kernel_launch(void* const* d_in, const int* in_sizes, int n_in,
                              void* d_out, int out_size, void* d_ws, size_t ws_size,
                              hipStream_t stream) {
    const float* logits = (const float*)d_in[0];
    const int* targets = (const int*)d_in[1];
    float* out = (float*)d_out;
    float* ws = (float*)d_ws;

    const size_t need = (size_t)30 * NBLOCKS * sizeof(float);   // 245,760 B
    if (ws_size >= need) {
        awce_main<false><<<NBLOCKS, THREADS, 0, stream>>>(logits, targets, ws);
        awce_final_partials<<<1, 512, 0, stream>>>(ws, out);
    } else {
        awce_zero_stats<<<1, 512, 0, stream>>>(ws);
        awce_main<true><<<NBLOCKS, THREADS, 0, stream>>>(logits, targets, ws);
        awce_final_atomic<<<1, 64, 0, stream>>>(ws, out);
    }
}

// Round 8
// 26.514 us; speedup vs baseline: 1.0165x; 1.0165x over previous
//
#include <hip/hip_runtime.h>

#define NCLS 10
#define IGN 10
#define HW_ (512 * 512)          // 262144 = 2^18
#define BATCH 8
#define NPIX (BATCH * HW_)       // 2097152
#define THREADS 256
#define PPT 8                    // px per thread (2 x float4 per channel)
#define BLOCK_PX (THREADS * PPT) // 2048
#define NBLOCKS (NPIX / BLOCK_PX)      // 1024 -> 4 blocks/CU, 16 waves/CU
#define STAT_STRIDE 16
#define LAMBDA_UNC 0.5f
#define LOG2E 1.4426950408889634f
#define LN2 0.6931471805599453f

// Per-thread private LDS histogram region: 33 floats (3 fields x 10 classes
// + 3 dump slots for ignore pixels). Stride 33 ≡ 1 (mod 32): self-zeroing
// write i hits bank (tid+i)%32 -> 2 lanes/bank (free); scatter offsets
// 3c+f land on distinct banks per thread.
#define RSTRIDE 33
#define HISTSZ (THREADS * RSTRIDE)   // 8448 floats = 33792 B

__global__ void awce_zero_stats(float* __restrict__ stats) {
    int i = threadIdx.x;
    if (i < 30 * STAT_STRIDE) stats[i] = 0.0f;
}

template <bool ATOMIC>
__global__ __launch_bounds__(THREADS, 4) void awce_main(
    const float* __restrict__ logits,
    const int* __restrict__ targets,
    float* __restrict__ outbuf)
{
    const int tid = threadIdx.x;
    const int wave = tid >> 6;
    const int lane = tid & 63;

    __shared__ float hist[HISTSZ];
    __shared__ float red[THREADS / 64][32];

    const int g0 = blockIdx.x * BLOCK_PX;      // 2048 | HW_ -> no batch cross
    const int b = g0 >> 18;
    const int hw0 = g0 & (HW_ - 1);
    const float* lbase = logits + (size_t)b * (NCLS * (size_t)HW_) + hw0;

    // ---- issue ALL 22 loads back-to-back (max MLP), pinned before compute ----
    float4 xl[2][NCLS];
    int4 tl[2];
#pragma unroll
    for (int h = 0; h < 2; ++h) {
        const int po = h * (4 * THREADS) + tid * 4;   // coalesced 4 KB per instr
#pragma unroll
        for (int c = 0; c < NCLS; ++c)
            xl[h][c] = *reinterpret_cast<const float4*>(lbase + (size_t)c * HW_ + po);
        tl[h] = *reinterpret_cast<const int4*>(targets + g0 + po);
    }
    // self-zero OWN hist region while loads fly -> no barrier needed before use
    float* hreg = &hist[tid * RSTRIDE];
#pragma unroll
    for (int i = 0; i < RSTRIDE; ++i) hreg[i] = 0.0f;
    __builtin_amdgcn_sched_barrier(0);   // don't sink loads into the compute

#pragma unroll
    for (int h = 0; h < 2; ++h) {
        const float4* xv = xl[h];
        const int tt[4] = {tl[h].x, tl[h].y, tl[h].z, tl[h].w};
#pragma unroll
        for (int j = 0; j < 4; ++j) {
            const int tj = tt[j];
            const int tc = (tj != IGN) ? tj : NCLS;   // NCLS -> dump slots
            float x[NCLS];
#pragma unroll
            for (int c = 0; c < NCLS; ++c)
                x[c] = (j == 0) ? xv[c].x : (j == 1) ? xv[c].y : (j == 2) ? xv[c].z : xv[c].w;
            float m = x[0];
#pragma unroll
            for (int c = 1; c < NCLS; ++c) m = fmaxf(m, x[c]);
            const float nm2 = -m * LOG2E;
            float sum = 0.f, dot = 0.f, xt = 0.f;
#pragma unroll
            for (int c = 0; c < NCLS; ++c) {
                const float e = __builtin_amdgcn_exp2f(fmaf(x[c], LOG2E, nm2));
                sum += e;
                dot = fmaf(e, x[c], dot);
                xt = (tc == c) ? x[c] : xt;
            }
            const float lse = fmaf(__builtin_amdgcn_logf(sum), LN2, m);
            const float rs = __builtin_amdgcn_rcpf(sum);
            const float ent = fmaf(-dot, rs, lse);
            const float ce = lse - xt;
            float* p = hreg + 3 * tc;
            p[0] += 1.0f;
            p[1] += ent;
            p[2] += ce;
        }
    }

    __syncthreads();   // all threads' hist RMWs visible for cross-region reduce

    // Stage 1: each wave reduces its 64 regions. Lane o<30: field f=o/10,
    // class c=o%10, region offset 3c+f (distinct 0..29 -> conflict-free).
    if (lane < 30) {
        const int f = (lane >= 20) ? 2 : ((lane >= 10) ? 1 : 0);
        const int c = lane - f * 10;
        const int off = 3 * c + f;
        float v = 0.f;
#pragma unroll
        for (int r = 0; r < 64; ++r) v += hist[(wave * 64 + r) * RSTRIDE + off];
        red[wave][lane] = v;
    }
    __syncthreads();

    // Stage 2: combine wave-partials; stat index = f*10+c = lane id.
    if (tid < 30) {
        float v = 0.f;
#pragma unroll
        for (int w = 0; w < THREADS / 64; ++w) v += red[w][tid];
        if (ATOMIC) {
            atomicAdd(&outbuf[tid * STAT_STRIDE], v);
        } else {
            outbuf[tid * NBLOCKS + blockIdx.x] = v;
        }
    }
}

// Reduce 30 x NBLOCKS partials, compute final loss. One block, 512 threads.
__global__ __launch_bounds__(512) void awce_final_partials(
    const float* __restrict__ partials, float* __restrict__ out)
{
    __shared__ float sred[32];
    const int wave = threadIdx.x >> 6;
    const int lane = threadIdx.x & 63;
#pragma unroll
    for (int k = 0; k < 4; ++k) {
        const int c = wave + k * 8;
        if (c < 30) {
            const float* col = partials + (size_t)c * NBLOCKS;
            float s = 0.f;
#pragma unroll
            for (int i = 0; i < NBLOCKS / 64; ++i) s += col[lane + 64 * i];
#pragma unroll
            for (int o = 32; o >= 1; o >>= 1) s += __shfl_xor(s, o);
            if (lane == 0) sred[c] = s;
        }
    }
    __syncthreads();
    if (threadIdx.x == 0) {
        float cnt[NCLS], es[NCLS], cs[NCLS];
        float nv = 0.f;
#pragma unroll
        for (int c = 0; c < NCLS; ++c) {
            cnt[c] = sred[c];
            es[c]  = sred[10 + c];
            cs[c]  = sred[20 + c];
            nv += cnt[c];
        }
        float loss = 0.f;
#pragma unroll
        for (int c = 0; c < NCLS; ++c) {
            float wb = 0.f;
            if (cnt[c] > 0.f && nv > 0.f) wb = (nv - cnt[c]) / fmaxf(nv, 1.f);
            const float em = (cnt[c] > 0.f) ? es[c] / fmaxf(cnt[c], 1.f) : 0.f;
            const float wc = wb * (1.f + LAMBDA_UNC * em);
            loss = fmaf(cs[c], wc, loss);
        }
        out[0] = loss / (nv + 1e-6f);
    }
}

__global__ void awce_final_atomic(const float* __restrict__ stats, float* __restrict__ out) {
    if (threadIdx.x == 0) {
        float cnt[NCLS], es[NCLS], cs[NCLS];
        float nv = 0.f;
#pragma unroll
        for (int c = 0; c < NCLS; ++c) {
            cnt[c] = stats[c * STAT_STRIDE];
            es[c]  = stats[(10 + c) * STAT_STRIDE];
            cs[c]  = stats[(20 + c) * STAT_STRIDE];
            nv += cnt[c];
        }
        float loss = 0.f;
#pragma unroll
        for (int c = 0; c < NCLS; ++c) {
            float wb = 0.f;
            if (cnt[c] > 0.f && nv > 0.f) wb = (nv - cnt[c]) / fmaxf(nv, 1.f);
            const float em = (cnt[c] > 0.f) ? es[c] / fmaxf(cnt[c], 1.f) : 0.f;
            const float wc = wb * (1.f + LAMBDA_UNC * em);
            loss = fmaf(cs[c], wc, loss);
        }
        out[0] = loss / (nv + 1e-6f);
    }
}

extern "C" void kernel_launch(void* const* d_in, const int* in_sizes, int n_in,
                              void* d_out, int out_size, void* d_ws, size_t ws_size,
                              hipStream_t stream) {
    const float* logits = (const float*)d_in[0];
    const int* targets = (const int*)d_in[1];
    float* out = (float*)d_out;
    float* ws = (float*)d_ws;

    const size_t need = (size_t)30 * NBLOCKS * sizeof(float);   // 122,880 B
    if (ws_size >= need) {
        awce_main<false><<<NBLOCKS, THREADS, 0, stream>>>(logits, targets, ws);
        awce_final_partials<<<1, 512, 0, stream>>>(ws, out);
    } else {
        awce_zero_stats<<<1, 512, 0, stream>>>(ws);
        awce_main<true><<<NBLOCKS, THREADS, 0, stream>>>(logits, targets, ws);
        awce_final_atomic<<<1, 64, 0, stream>>>(ws, out);
    }
}